// Round 6
// baseline (613.438 us; speedup 1.0000x reference)
//
#include <hip/hip_runtime.h>

// Segment-sum via (window, bucket) scatter + L3-windowed pipelined gather.
// H: [N=1.6M, 128] f32, X_node: [N] i32, out: [V=50000, 128] f32.
//
// Idea: the bucket-major gather is a *permutation* of a streaming read of H;
// random 512B reads run at ~3 TB/s (DRAM row-activate bound) vs 6.3 TB/s
// streaming. So: split rows into W=16 windows of ~51 MB. Scatter bins rows by
// (window, bucket). One resident reduce kernel keeps per-bucket accumulators
// in registers and loops windows: stream-prefetch window w+1 sequentially
// (fills the 256MB memory-side Infinity Cache at full DRAM BW) while
// gathering window w's rows out of L3. DRAM sees ~only sequential traffic.
// Correctness does NOT depend on L3 behavior; overflow list keeps it correct
// for any index distribution.

#define D 128
#define BLOCK 256
#define W 16        // row windows (N/W rows each, ~51.2 MB)
#define CAPW 16     // slots per (window, bucket); lambda = 2 expected
#define BPW 13      // buckets per wave (ceil(50000 / 3848))

typedef float f2 __attribute__((ext_vector_type(2)));
typedef float f4 __attribute__((ext_vector_type(4)));

// ---------------- phase 1: windowed scatter ----------------
__global__ void scatter_kernel(const int* __restrict__ idx, int* __restrict__ cnt,
                               int* __restrict__ order, int* __restrict__ ovf_meta,
                               int* __restrict__ ovf, int n, int rpw, int V) {
    int i = blockIdx.x * blockDim.x + threadIdx.x;
    int stride = gridDim.x * blockDim.x;
    for (; i < n; i += stride) {
        const int v = idx[i];
        const int w = i / rpw;                 // window of row i
        const int cell = w * V + v;            // window-major: scatter locality
        const int p = atomicAdd(&cnt[cell], 1);
        if (p < CAPW) order[(size_t)cell * CAPW + p] = i;
        else { int q = atomicAdd(ovf_meta, 1); ovf[q] = i; }
    }
}

// ---------------- phase 2: windowed gather + reduce ----------------
__global__ void __launch_bounds__(BLOCK, 4) reduce_kernel(
        const f2* __restrict__ H2, const f4* __restrict__ H4,
        const int* __restrict__ cnt, const int* __restrict__ order,
        f2* __restrict__ out, int V, int N, int rpw, int nwaves) {
    const int gid  = blockIdx.x * blockDim.x + threadIdx.x;
    const int wv   = gid >> 6;
    const int lane = gid & 63;           // lane owns float2 column `lane`
    const int b0   = wv * BPW;           // first bucket of this wave

    f2 acc[BPW];
#pragma unroll
    for (int b = 0; b < BPW; ++b) acc[b] = (f2){0.f, 0.f};

    const long h4n = (long)N * 32;       // total float4s in H
    const long w4  = (long)rpw * 32;     // float4s per window
    // per-lane prefetch loads per window (distributed over all launched waves)
    const int pfl = (int)((w4 + (long)nwaves * 64 - 1) / ((long)nwaves * 64));

    float sink = 0.f;

    // prologue: stream window 0 into L3
    {
        const long we = (w4 < h4n) ? w4 : h4n;
        long p = (long)wv * (pfl * 64) + lane;
        for (int k = 0; k < pfl; ++k, p += 64) {
            if (p < we) { const f4 t = H4[p]; sink += t.x; }
        }
    }

#pragma unroll 1
    for (int w = 0; w < W; ++w) {
        // stream-prefetch window w+1 (pure perf hint; correctness-independent)
        if (w + 1 < W) {
            const long wb = (long)(w + 1) * w4;
            long we = wb + w4; if (we > h4n) we = h4n;
            long p = wb + (long)wv * (pfl * 64) + lane;
            for (int k = 0; k < pfl; ++k, p += 64) {
                if (p < we) { const f4 t = H4[p]; sink += t.x; }
            }
        }
        // gather this wave's buckets within window w (expected L3-hot)
#pragma unroll
        for (int b = 0; b < BPW; ++b) {
            const int v = b0 + b;
            if (v < V) {
                const int cell = w * V + v;
                int c = cnt[cell]; c = (c > CAPW) ? CAPW : c;
                const int* op = order + (size_t)cell * CAPW;
                for (int g = 0; g < c; g += 2) {
                    const int2 iv = *(const int2*)(op + g);          // 8B-aligned
                    const int  j1 = (g + 1 < c) ? iv.y : iv.x;       // pad = same row (L1 hit)
                    const f2 a0 = H2[(size_t)(unsigned)iv.x * 64 + lane];
                    const f2 a1 = H2[(size_t)(unsigned)j1   * 64 + lane];
                    const float m1 = (g + 1 < c) ? 1.f : 0.f;
                    acc[b].x += a0.x;
                    acc[b].y += a0.y;
                    acc[b].x = fmaf(m1, a1.x, acc[b].x);
                    acc[b].y = fmaf(m1, a1.y, acc[b].y);
                }
            }
        }
    }
    asm volatile("" :: "v"(sink));   // keep prefetch loads live

#pragma unroll
    for (int b = 0; b < BPW; ++b) {
        const int v = b0 + b;
        if (v < V) out[(size_t)v * 64 + lane] = acc[b];
    }
}

// ---------------- phase 3: overflow fix-up (expected no-op) ----------------
__global__ void ovf_fix_kernel(const f2* __restrict__ H2, const int* __restrict__ idx,
                               const int* __restrict__ ovf_meta, const int* __restrict__ ovf,
                               float* __restrict__ out) {
    const int novf = *ovf_meta;
    if (novf <= 0) return;
    const int gid  = blockIdx.x * blockDim.x + threadIdx.x;
    const int wave = gid >> 6;
    const int lane = gid & 63;
    const int nwaves = (gridDim.x * blockDim.x) >> 6;
    for (int o = wave; o < novf; o += nwaves) {
        const int row = ovf[o];
        const int v   = idx[row];
        const f2 a = H2[(size_t)(unsigned)row * 64 + lane];
        atomicAdd(&out[((size_t)v << 7) | ((unsigned)lane << 1)],       a.x);
        atomicAdd(&out[(((size_t)v << 7) | ((unsigned)lane << 1)) + 1], a.y);
    }
}

extern "C" void kernel_launch(void* const* d_in, const int* in_sizes, int n_in,
                              void* d_out, int out_size, void* d_ws, size_t ws_size,
                              hipStream_t stream) {
    const float* H      = (const float*)d_in[0];
    const int*   X_node = (const int*)d_in[1];
    const int N = in_sizes[1];
    const int V = out_size / D;
    float* out = (float*)d_out;

    const int rpw = (N + W - 1) / W;       // rows per window (100,000)

    // ws layout: cnt[V*W] | ovf_meta[1] | ovf[N] | order[V*W*CAPW]
    int* cnt      = (int*)d_ws;
    int* ovf_meta = cnt + (size_t)V * W;
    int* ovf      = ovf_meta + 1;
    int* order    = ovf + N;

    hipMemsetAsync(cnt, 0, ((size_t)V * W + 1) * sizeof(int), stream);

    scatter_kernel<<<2048, BLOCK, 0, stream>>>(X_node, cnt, order, ovf_meta, ovf,
                                               N, rpw, V);

    const int nwaves = (V + BPW - 1) / BPW;        // 3847
    const int blocks = (nwaves + 3) / 4;           // 962  (all resident at >=4 blk/CU)
    reduce_kernel<<<blocks, BLOCK, 0, stream>>>(
        (const f2*)H, (const f4*)H, cnt, order, (f2*)out, V, N, rpw, blocks * 4);

    ovf_fix_kernel<<<16, BLOCK, 0, stream>>>((const f2*)H, X_node, ovf_meta, ovf, out);
}

// Round 7
// 335.615 us; speedup vs baseline: 1.8278x; 1.8278x over previous
//
#include <hip/hip_runtime.h>

// Segment-sum via (window, wave-cell) scatter + L3-windowed pipelined gather.
// H: [N=1.6M, 128] f32, X_node: [N] i32, out: [V=50000, 128] f32.
//
// R6 post-mortem fixes:
//  - prefetch via global_load_lds into throwaway LDS (no VGPR, never consumed
//    -> never forces a vmcnt drain)
//  - issue order per window: [cnt + idx loads] -> [prefetch w+1] -> wait idx
//    (counted vmcnt keeps prefetch in flight) -> [<=64 independent row loads]
//    -> drain = max(gather, stream)  == the pipeline overlap point
//  - one flat row list per (window, wave) cell (bucket packed in low 4 bits)
//    instead of 13 serialized per-bucket loops; accumulate in LDS acc[13][128].

#define D 128
#define BLOCK 256
#define W 16        // row windows (~51.2 MB each)
#define BPW 13      // buckets per wave
#define CAP 64      // slots per (window, wave) cell; lambda ~= 26

typedef float f2 __attribute__((ext_vector_type(2)));

typedef const __attribute__((address_space(1))) char GChar;
typedef __attribute__((address_space(3))) char LChar;

// ---------------- phase 1: windowed scatter ----------------
__global__ void scatter_kernel(const int* __restrict__ idx, int* __restrict__ cnt,
                               int* __restrict__ order, int* __restrict__ ovf_meta,
                               int* __restrict__ ovf, int n, int rpw, int NW) {
    int i = blockIdx.x * blockDim.x + threadIdx.x;
    int stride = gridDim.x * blockDim.x;
    for (; i < n; i += stride) {
        const int v  = idx[i];
        const int w  = i / rpw;
        const int wv = (unsigned)v / BPW;          // wave owning bucket v
        const int bl = v - wv * BPW;               // bucket-local 0..12
        const int cell = w * NW + wv;
        const int p = atomicAdd(&cnt[cell], 1);
        if (p < CAP) order[(size_t)cell * CAP + p] = (i << 4) | bl;
        else { int q = atomicAdd(ovf_meta, 1); ovf[q] = i; }
    }
}

// ---------------- phase 2: windowed pipelined gather + reduce ----------------
__global__ void __launch_bounds__(BLOCK, 4) reduce_kernel(
        const f2* __restrict__ H2, const char* __restrict__ Hc,
        const int* __restrict__ cnt, const int* __restrict__ order,
        f2* __restrict__ out, int V, int N, int rpw, int NW, int nwaves) {
    __shared__ float accs[BLOCK / 64][BPW][D];          // 26,624 B
    __shared__ __align__(16) char pfbuf[BLOCK / 64][1024];

    const int tid  = threadIdx.x;
    const int wl   = tid >> 6;
    const int lane = tid & 63;
    const int wv   = blockIdx.x * (BLOCK / 64) + wl;
    const bool active = (wv < NW);
    const int b0 = wv * BPW;

#pragma unroll
    for (int b = 0; b < BPW; ++b) {
        accs[wl][b][lane * 2]     = 0.f;
        accs[wl][b][lane * 2 + 1] = 0.f;
    }

    const long h4n = (long)N * 32;            // total float4s in H
    const long w4  = (long)rpw * 32;          // float4s per window
    const int  pfl = (int)((w4 + (long)nwaves * 64 - 1) / ((long)nwaves * 64));
    LChar* ldsdst = (LChar*)&pfbuf[wl][0];    // wave-uniform dest (content unused)

#pragma unroll 1
    for (int w = 0; w < W; ++w) {
        // ---- 1. issue cnt + first 8 index int4 loads (independent) ----
        int c = 0;
        int4 q[16];
        const int4* qp = nullptr;
        if (active) {
            const int cell = w * NW + wv;
            c  = cnt[cell];
            qp = (const int4*)(order + (size_t)cell * CAP);
#pragma unroll
            for (int k = 0; k < 8; ++k) q[k] = qp[k];
        }
        // ---- 2. fire-and-forget prefetch of window w+1 into L2/L3 ----
        if (w + 1 < W) {
            const long wb = (long)(w + 1) * w4;
            long p = wb + (long)wv * ((long)pfl * 64) + lane;
#pragma unroll 1
            for (int k = 0; k < pfl; ++k, p += 64) {
                long pp = (p < h4n) ? p : (h4n - 1);
                __builtin_amdgcn_global_load_lds((GChar*)(Hc + pp * 16), ldsdst, 16, 0, 0);
            }
        }
        // ---- 3. process rows (waits on idx via counted vmcnt; prefetch stays in flight)
        if (active && c > 0) {
            const int cc = (c > CAP) ? CAP : c;
            if (cc > 32) {                    // rare tail (P ~ 10%): late idx loads
#pragma unroll
                for (int k = 8; k < 16; ++k) q[k] = qp[k];
            }
#pragma unroll
            for (int k = 0; k < 8; ++k) {
                const int g = k * 8;
                if (g < cc) {
                    const int4 qa = q[2 * k], qb = q[2 * k + 1];
                    const int e[8] = {qa.x, qa.y, qa.z, qa.w, qb.x, qb.y, qb.z, qb.w};
#pragma unroll
                    for (int j = 0; j < 8; ++j) {
                        const bool val = (g + j < cc);
                        const int row = val ? ((unsigned)e[j] >> 4) : 0;
                        const f2 a = H2[(size_t)row * 64 + lane];
                        const float m = val ? 1.f : 0.f;
                        const int bl = val ? (e[j] & 15) : 0;
                        float* s = &accs[wl][bl][lane * 2];
                        s[0] = fmaf(m, a.x, s[0]);
                        s[1] = fmaf(m, a.y, s[1]);
                    }
                }
            }
        }
    }

    if (active) {
#pragma unroll
        for (int b = 0; b < BPW; ++b) {
            const int v = b0 + b;
            if (v < V) {
                f2 r = {accs[wl][b][lane * 2], accs[wl][b][lane * 2 + 1]};
                out[(size_t)v * 64 + lane] = r;
            }
        }
    }
}

// ---------------- phase 3: overflow fix-up (expected no-op) ----------------
__global__ void ovf_fix_kernel(const f2* __restrict__ H2, const int* __restrict__ idx,
                               const int* __restrict__ ovf_meta, const int* __restrict__ ovf,
                               float* __restrict__ out) {
    const int novf = *ovf_meta;
    if (novf <= 0) return;
    const int gid  = blockIdx.x * blockDim.x + threadIdx.x;
    const int wave = gid >> 6;
    const int lane = gid & 63;
    const int nwaves = (gridDim.x * blockDim.x) >> 6;
    for (int o = wave; o < novf; o += nwaves) {
        const int row = ovf[o];
        const int v   = idx[row];
        const f2 a = H2[(size_t)(unsigned)row * 64 + lane];
        atomicAdd(&out[((size_t)v << 7) | ((unsigned)lane << 1)],       a.x);
        atomicAdd(&out[(((size_t)v << 7) | ((unsigned)lane << 1)) + 1], a.y);
    }
}

extern "C" void kernel_launch(void* const* d_in, const int* in_sizes, int n_in,
                              void* d_out, int out_size, void* d_ws, size_t ws_size,
                              hipStream_t stream) {
    const float* H      = (const float*)d_in[0];
    const int*   X_node = (const int*)d_in[1];
    const int N = in_sizes[1];
    const int V = out_size / D;
    float* out = (float*)d_out;

    const int rpw   = (N + W - 1) / W;          // rows per window (100,000)
    const int NW    = (V + BPW - 1) / BPW;      // waves (3847)
    const int cells = W * NW;                   // 61,552

    // ws layout: order[cells*CAP] (16B-aligned first) | cnt[cells] | ovf_meta | ovf[N]
    int* order    = (int*)d_ws;
    int* cnt      = order + (size_t)cells * CAP;
    int* ovf_meta = cnt + cells;
    int* ovf      = ovf_meta + 1;

    hipMemsetAsync(cnt, 0, ((size_t)cells + 1) * sizeof(int), stream);

    scatter_kernel<<<2048, BLOCK, 0, stream>>>(X_node, cnt, order, ovf_meta, ovf,
                                               N, rpw, NW);

    const int blocks = (NW + (BLOCK / 64) - 1) / (BLOCK / 64);   // 962
    const int nwaves = blocks * (BLOCK / 64);                    // 3848
    reduce_kernel<<<blocks, BLOCK, 0, stream>>>(
        (const f2*)H, (const char*)H, cnt, order, (f2*)out, V, N, rpw, NW, nwaves);

    ovf_fix_kernel<<<16, BLOCK, 0, stream>>>((const f2*)H, X_node, ovf_meta, ovf, out);
}